// Round 4
// baseline (157.985 us; speedup 1.0000x reference)
//
#include <hip/hip_runtime.h>
#include <hip/hip_bf16.h>
#include <stdint.h>

typedef unsigned short u16;
typedef __attribute__((ext_vector_type(8))) short bf16x8;
typedef __attribute__((ext_vector_type(4))) float f32x4;
typedef __attribute__((ext_vector_type(16))) float f32x16;

typedef __attribute__((address_space(1))) const void gas_t;
typedef __attribute__((address_space(3))) void las_t;

#define DEV __device__ __forceinline__

DEV float bf2f(u16 v){ union{uint32_t u; float f;} x; x.u = ((uint32_t)v)<<16; return x.f; }
DEV u16 f2bf(float f){ union{float f; uint32_t u;} x; x.f=f; uint32_t r = x.u + 0x7fff + ((x.u>>16)&1u); return (u16)(r>>16); }

// packed f32 pair -> 2x bf16 (RNE)
DEV uint32_t pk2(float a, float b){
  return (uint32_t)f2bf(a) | ((uint32_t)f2bf(b)<<16);
}

// cross-half (lane<32 <-> lane>=32) pairwise exchange:
// ra = hi? b_from_partner : a ;  rb = hi? b : a_from_partner
DEV void xswap(uint32_t a, uint32_t b, int hi, uint32_t& ra, uint32_t& rb){
#if __has_builtin(__builtin_amdgcn_permlane32_swap)
  auto r = __builtin_amdgcn_permlane32_swap((int)a, (int)b, false, false);
  ra = (uint32_t)r[0]; rb = (uint32_t)r[1];
#else
  uint32_t sa = (uint32_t)__shfl_xor((int)a, 32);
  uint32_t sb = (uint32_t)__shfl_xor((int)b, 32);
  ra = hi ? sb : a;
  rb = hi ? b  : sa;
#endif
}

DEV void gload_lds16(const u16* g, u16* l){
  __builtin_amdgcn_global_load_lds((gas_t*)g, (las_t*)l, 16, 0, 0);
}

// ---------------- fp32 -> bf16 convert ----------------
__global__ void cvt_f32_bf16(const float* __restrict__ src, u16* __restrict__ dst, int n4){
  int i = blockIdx.x*blockDim.x + threadIdx.x;
  if(i < n4){
    float4 v = ((const float4*)src)[i];
    ushort4 o; o.x=f2bf(v.x); o.y=f2bf(v.y); o.z=f2bf(v.z); o.w=f2bf(v.w);
    ((ushort4*)dst)[i] = o;
  }
}

// ---------------- bf16 GEMM: C[M,N] = A[M,K] * B[N,K]^T + bias ----------------
template<int OUT_F32>
__global__ __launch_bounds__(256,2)
void gemm_bt(const u16* __restrict__ A, const u16* __restrict__ Bw,
             const float* __restrict__ bias, void* __restrict__ Cp, int N)
{
  constexpr int BK = 32, KSTEPS = 1024/BK;
  __shared__ __align__(16) u16 As[128][BK];
  __shared__ __align__(16) u16 Bs[128][BK];
  const int tid = threadIdx.x, w = tid>>6, l = tid&63;
  const int a = l&15, g = l>>4;
  const int m0 = blockIdx.y*128, n0 = blockIdx.x*128;
  const int wr = w>>1, wc = w&1;
  f32x4 zero = {0.f,0.f,0.f,0.f};
  f32x4 acc[4][4];
  #pragma unroll
  for(int m=0;m<4;m++) for(int n=0;n<4;n++) acc[m][n]=zero;

  const int srow = l>>2, scol = (l&3)*8;
  const u16* Ag = A  + (size_t)(m0 + w*32 + srow)*1024 + scol;
  const u16* Bg = Bw + (size_t)(n0 + w*32 + srow)*1024 + scol;

  for(int kt=0; kt<KSTEPS; ++kt){
    if(kt) __syncthreads();
    gload_lds16(Ag + kt*BK,           &As[w*32   ][0]);
    gload_lds16(Ag + kt*BK + 16*1024, &As[w*32+16][0]);
    gload_lds16(Bg + kt*BK,           &Bs[w*32   ][0]);
    gload_lds16(Bg + kt*BK + 16*1024, &Bs[w*32+16][0]);
    __syncthreads();
    bf16x8 af[4], bf[4];
    #pragma unroll
    for(int m=0;m<4;m++) af[m] = *(const bf16x8*)&As[wr*64 + m*16 + a][g*8];
    #pragma unroll
    for(int n=0;n<4;n++) bf[n] = *(const bf16x8*)&Bs[wc*64 + n*16 + a][g*8];
    #pragma unroll
    for(int m=0;m<4;m++)
      #pragma unroll
      for(int n=0;n<4;n++)
        acc[m][n] = __builtin_amdgcn_mfma_f32_16x16x32_bf16(af[m], bf[n], acc[m][n], 0,0,0);
  }
  #pragma unroll
  for(int n=0;n<4;n++){
    int col = n0 + wc*64 + n*16 + a;
    float bv = bias[col];
    #pragma unroll
    for(int m=0;m<4;m++){
      int row = m0 + wr*64 + m*16 + g*4;
      #pragma unroll
      for(int r=0;r<4;r++){
        float v = acc[m][n][r] + bv;
        if(OUT_F32) ((float*)Cp)[(size_t)(row+r)*N + col] = v;
        else        ((u16*)Cp)[(size_t)(row+r)*N + col] = f2bf(v);
      }
    }
  }
}

// ---------------- RoPE + relayout q,k: qkv[4096][3072] -> q,k [B*H][S][64] ----------------
__global__ void rope_relayout(const u16* __restrict__ qkv, u16* __restrict__ q_r,
                              u16* __restrict__ k_r)
{
  int t = blockIdx.x*256 + threadIdx.x;
  int gI = t&3, h=(t>>2)&15, row=t>>6;
  int s = row & 2047, b = row >> 11;
  int d0 = gI*8;
  const u16* base = qkv + (size_t)row*3072 + h*64 + d0;
  union U { uint4 v; u16 e[8]; };
  U q1,q2,k1,k2, oq1,oq2,ok1,ok2;
  q1.v = *(const uint4*)(base);
  q2.v = *(const uint4*)(base+32);
  k1.v = *(const uint4*)(base+1024);
  k2.v = *(const uint4*)(base+1024+32);
  #pragma unroll
  for(int j=0;j<8;j++){
    float d = (float)(d0+j);
    float fr = __expf(-0.28782313662425574f * d);
    float ang = (float)s * fr;
    float sn, cs; sincosf(ang, &sn, &cs);
    float x1 = bf2f(q1.e[j]), x2 = bf2f(q2.e[j]);
    oq1.e[j] = f2bf(x1*cs - x2*sn); oq2.e[j] = f2bf(x1*sn + x2*cs);
    x1 = bf2f(k1.e[j]); x2 = bf2f(k2.e[j]);
    ok1.e[j] = f2bf(x1*cs - x2*sn); ok2.e[j] = f2bf(x1*sn + x2*cs);
  }
  size_t o = ((size_t)(b*16+h)*2048 + s)*64 + d0;
  *(uint4*)(q_r+o) = oq1.v; *(uint4*)(q_r+o+32) = oq2.v;
  *(uint4*)(k_r+o) = ok1.v; *(uint4*)(k_r+o+32) = ok2.v;
}

// ---------------- V transpose: qkv[...][2048 + h*64 + d] -> vt[bh][d][s] ----------------
// grid: 512 blocks (32 bh x 16 s-tiles of 128), 256 threads.
__global__ __launch_bounds__(256,2)
void v_transpose(const u16* __restrict__ qkv, u16* __restrict__ vt)
{
  __shared__ uint32_t L[64*65];     // [d][s-pair], dword pitch 65 (bank-spread)
  const int tid = threadIdx.x;
  const int bh = blockIdx.x & 31;
  const int stile = blockIdx.x >> 5;
  const int b = bh >> 4, h = bh & 15;
  const int s0 = stile*128;
  const int cg = tid & 7, sr = tid >> 3;          // cg: 8-col group, sr: 0..31
  const u16* src = qkv + (size_t)(b*2048 + s0)*3072 + 2048 + h*64 + cg*8;
  #pragma unroll
  for(int p=0;p<2;p++){
    int srow = p*64 + sr*2;
    union{uint4 v; u16 e[8];} v0, v1;
    v0.v = *(const uint4*)(src + (size_t)srow*3072);
    v1.v = *(const uint4*)(src + (size_t)(srow+1)*3072);
    #pragma unroll
    for(int jj=0;jj<8;jj++)
      L[(cg*8+jj)*65 + p*32 + sr] = (uint32_t)v0.e[jj] | ((uint32_t)v1.e[jj]<<16);
  }
  __syncthreads();
  const int w = tid>>6, ln = tid&63;
  u16* dst = vt + (size_t)bh*64*2048 + s0;
  #pragma unroll
  for(int dd=0;dd<16;dd++){
    int d = w*16 + dd;
    *(uint32_t*)(dst + (size_t)d*2048 + ln*2) = L[d*65 + ln];
  }
}

// ---------------- wave-autonomous causal flash attention ----------------
// Q,K: [B*H][2048][64] bf16 (rope'd). VT: [B*H][64][2048] bf16. O: [4096][1024] bf16.
// One 64-thread block = one wave = one 32-row q-tile. Swapped QK^T and swapped PV
// (32x32x16 MFMA), q lane-local (lane&31). Register prefetch of next K/V tile.
__global__ __launch_bounds__(64,2)
void attn_fwd3(const u16* __restrict__ Q, const u16* __restrict__ K,
               const u16* __restrict__ VT, u16* __restrict__ O)
{
  const int l = threadIdx.x;
  const int lo = l&31, hi = l>>5;
  const int b0 = blockIdx.x;          // 2048 blocks
  const int bh = b0 & 31;             // head  (XCD gets 4 heads)
  const int j  = b0 >> 5;             // q-tile 0..63 (CU gets {y,y+8,..,y+56})
  const int q0 = j*32;

  const u16* Qb = Q  + ((size_t)bh*2048 + q0)*64;
  const u16* Kb = K  + (size_t)bh*2048*64;
  const u16* Vt = VT + (size_t)bh*64*2048;

  bf16x8 qf[4];
  #pragma unroll
  for(int s=0;s<4;s++) qf[s] = *(const bf16x8*)(Qb + lo*64 + s*16 + hi*8);

  const u16* kl = Kb + lo*64 + hi*8;        // + t*2048  + s*16
  const u16* vl = Vt + lo*2048 + hi*8;      // + dt*65536 + t*32 + s2*16

  f32x16 oacc0, oacc1;
  #pragma unroll
  for(int r=0;r<16;r++){ oacc0[r]=0.f; oacc1[r]=0.f; }
  float m_run = -1e30f, l_run = 0.f;

  bf16x8 kc[4], vc[4];
  #pragma unroll
  for(int s=0;s<4;s++) kc[s] = *(const bf16x8*)(kl + s*16);
  #pragma unroll
  for(int dt=0;dt<2;dt++)
    #pragma unroll
    for(int s2=0;s2<2;s2++) vc[dt*2+s2] = *(const bf16x8*)(vl + dt*65536 + s2*16);

  for(int t=0; t<=j; ++t){
    bf16x8 kn[4], vn[4];
    if(t < j){
      const u16* kt2 = kl + (size_t)(t+1)*2048;
      const u16* vt2 = vl + (t+1)*32;
      #pragma unroll
      for(int s=0;s<4;s++) kn[s] = *(const bf16x8*)(kt2 + s*16);
      #pragma unroll
      for(int dt=0;dt<2;dt++)
        #pragma unroll
        for(int s2=0;s2<2;s2++) vn[dt*2+s2] = *(const bf16x8*)(vt2 + dt*65536 + s2*16);
    }

    // S^T[kv][q]: col=q=lo, row kv_l=(r&3)+8*(r>>2)+4*hi
    f32x16 st;
    #pragma unroll
    for(int r=0;r<16;r++) st[r]=0.f;
    #pragma unroll
    for(int s=0;s<4;s++)
      st = __builtin_amdgcn_mfma_f32_32x32x16_bf16(kc[s], qf[s], st, 0,0,0);

    float sv[16];
    #pragma unroll
    for(int r=0;r<16;r++) sv[r] = st[r]*0.125f;
    if(t==j){
      #pragma unroll
      for(int r=0;r<16;r++){
        const int kvl = (r&3)+8*(r>>2);
        sv[r] = (kvl + 4*hi <= lo) ? sv[r] : -1e30f;
      }
    }

    float m8[8];
    #pragma unroll
    for(int i=0;i<8;i++) m8[i] = fmaxf(sv[i], sv[i+8]);
    #pragma unroll
    for(int s=4;s>=1;s>>=1)
      #pragma unroll
      for(int i=0;i<s;i++) m8[i] = fmaxf(m8[i], m8[i+s]);
    float pmax = fmaxf(m8[0], __shfl_xor(m8[0], 32));

    if(!__all(pmax <= m_run + 8.f)){
      float mnew = fmaxf(m_run, pmax);
      float corr = __expf(m_run - mnew);
      l_run *= corr;
      #pragma unroll
      for(int r=0;r<16;r++){ oacc0[r]*=corr; oacc1[r]*=corr; }
      m_run = mnew;
    }

    float p[16];
    #pragma unroll
    for(int r=0;r<16;r++) p[r] = __expf(sv[r] - m_run);
    float sm[8];
    #pragma unroll
    for(int i=0;i<8;i++) sm[i] = p[i] + p[i+8];
    #pragma unroll
    for(int s=4;s>=1;s>>=1)
      #pragma unroll
      for(int i=0;i<s;i++) sm[i] += sm[i+s];
    l_run += sm[0] + __shfl_xor(sm[0], 32);

    uint32_t pk[8];
    #pragma unroll
    for(int i=0;i<8;i++) pk[i] = pk2(p[2*i], p[2*i+1]);

    union PF { bf16x8 v; uint32_t u[4]; } pf0, pf1;
    xswap(pk[0], pk[2], hi, pf0.u[0], pf0.u[2]);
    xswap(pk[1], pk[3], hi, pf0.u[1], pf0.u[3]);
    xswap(pk[4], pk[6], hi, pf1.u[0], pf1.u[2]);
    xswap(pk[5], pk[7], hi, pf1.u[1], pf1.u[3]);

    // O^T[d][q] += V^T[d][kv] * P[q][kv]
    oacc0 = __builtin_amdgcn_mfma_f32_32x32x16_bf16(vc[0], pf0.v, oacc0, 0,0,0);
    oacc0 = __builtin_amdgcn_mfma_f32_32x32x16_bf16(vc[1], pf1.v, oacc0, 0,0,0);
    oacc1 = __builtin_amdgcn_mfma_f32_32x32x16_bf16(vc[2], pf0.v, oacc1, 0,0,0);
    oacc1 = __builtin_amdgcn_mfma_f32_32x32x16_bf16(vc[3], pf1.v, oacc1, 0,0,0);

    if(t < j){
      #pragma unroll
      for(int i=0;i<4;i++){ kc[i]=kn[i]; vc[i]=vn[i]; }
    }
  }

  const float invl = 1.f / l_run;
  const int row_g = (bh>>4)*2048 + q0 + lo;
  u16* Ob = O + (size_t)row_g*1024 + (bh&15)*64;
  #pragma unroll
  for(int g2=0; g2<4; g2++){
    uint2 pr;
    pr.x = pk2(oacc0[4*g2+0]*invl, oacc0[4*g2+1]*invl);
    pr.y = pk2(oacc0[4*g2+2]*invl, oacc0[4*g2+3]*invl);
    *(uint2*)(Ob + 8*g2 + 4*hi) = pr;
  }
  #pragma unroll
  for(int g2=0; g2<4; g2++){
    uint2 pr;
    pr.x = pk2(oacc1[4*g2+0]*invl, oacc1[4*g2+1]*invl);
    pr.y = pk2(oacc1[4*g2+2]*invl, oacc1[4*g2+3]*invl);
    *(uint2*)(Ob + 32 + 8*g2 + 4*hi) = pr;
  }
}

extern "C" void kernel_launch(void* const* d_in, const int* in_sizes, int n_in,
                              void* d_out, int out_size, void* d_ws, size_t ws_size,
                              hipStream_t stream)
{
  const float* x      = (const float*)d_in[0];
  const float* qkv_w  = (const float*)d_in[1];
  const float* qkv_b  = (const float*)d_in[2];
  const float* proj_w = (const float*)d_in[3];
  const float* proj_b = (const float*)d_in[4];
  float* out = (float*)d_out;
  char* ws = (char*)d_ws;

  u16* xb    = (u16*)(ws);                          // 8 MB (reused as attn O)
  u16* wqkv  = (u16*)(ws + 8388608);                // 6 MB
  u16* wproj = (u16*)(ws + 8388608 + 6291456);      // 2 MB
  u16* qkvr  = (u16*)(ws + 16777216);               // 24 MB
  u16* q_r   = (u16*)(ws + 41943040);               // 8 MB
  u16* k_r   = q_r + 4194304;                       // 8 MB
  u16* vt    = k_r + 4194304;                       // 8 MB (V^T)
  u16* o_b   = xb;

  cvt_f32_bf16<<<4096,256,0,stream>>>(x, xb, 1048576);
  cvt_f32_bf16<<<3072,256,0,stream>>>(qkv_w, wqkv, 786432);
  cvt_f32_bf16<<<1024,256,0,stream>>>(proj_w, wproj, 262144);

  dim3 gA(24,32);
  gemm_bt<0><<<gA,256,0,stream>>>(xb, wqkv, qkv_b, qkvr, 3072);

  rope_relayout<<<1024,256,0,stream>>>(qkvr, q_r, k_r);
  v_transpose<<<512,256,0,stream>>>(qkvr, vt);

  attn_fwd3<<<2048,64,0,stream>>>(q_r, k_r, vt, o_b);

  dim3 gC(8,32);
  gemm_bt<1><<<gC,256,0,stream>>>(o_b, wproj, proj_b, out, 1024);
}